// Round 7
// baseline (2331.481 us; speedup 1.0000x reference)
//
#include <hip/hip_runtime.h>

typedef unsigned int u32;
typedef unsigned short u16;

#define BG 64
#define NNODE 320
#define NEDGE 1280
#define TT 256
#define FN 64
#define FG 16
#define HM 128
#define HU 128
#define HG 64
#define HA 4
#define ZM 512
#define ZU 512
#define ZG 256
#define ZA 16
#define DM 144
#define DU 208
#define DG 144
#define DA 192

// ---- conversion-area layout (floats, relative to ws+64) ----
// WmT/WuT/WgT/WaT are stored TRANSPOSED (din-major) for coalesced projection
// kernels. Whh_m/Whh_u/Whg/Wha stay row-major (per-thread register loads).
#define CV 64
#define O_NODES 0
#define O_GA    20480
#define O_WM    21504
#define O_WHM   95232
#define O_BM    160768
#define O_WU    161280
#define O_WHU   267776
#define O_BU    333312
#define O_WG    333824
#define O_WHG   370688
#define O_BG2   387072
#define O_WA    387328
#define O_WHA   390400
#define O_BA    390464
#define CONV_TOTAL 390480
#define O_XZM   390528
#define O_MSG   (O_XZM + 320 * ZM)
#define O_XZU   (O_XZM + NEDGE * ZM)
#define O_XZG   (O_XZU + NNODE * ZU)
#define O_XZA   (O_XZG + BG * ZG)
#define O_AGGR  (O_XZA + BG * ZA)
#define O_AGGB  (O_AGGR + NNODE * HM)
#define O_UPD   (O_AGGB + BG * HU)
#define WS_FLOATS (CV + O_UPD + NNODE * HU)

__device__ __forceinline__ float bf2f(u16 v) {
  return __uint_as_float(((u32)v) << 16);
}
__device__ __forceinline__ float sigf(float x) { return 1.0f / (1.0f + __expf(-x)); }
__device__ __forceinline__ float tanh_(float x) {
  float e = __expf(-2.0f * fabsf(x));
  float t = (1.0f - e) / (1.0f + e);
  return copysignf(t, x);
}
__device__ __forceinline__ float cvt(const void* p, int i, int flag) {
  return flag ? bf2f(((const u16*)p)[i]) : ((const float*)p)[i];
}

// lgkmcnt-only barrier: orders LDS without __syncthreads()'s vmcnt(0) drain.
#define BAR() asm volatile("s_waitcnt lgkmcnt(0)\n\ts_barrier" ::: "memory")

// 4-lane (quad) butterfly sum on the VALU pipe via DPP quad_perm — no DS ops.
__device__ __forceinline__ float quad_sum(float s) {
  float t;
  t = __uint_as_float(__builtin_amdgcn_update_dpp(
      0, (int)__float_as_uint(s), 0xB1 /*[1,0,3,2]*/, 0xF, 0xF, true));
  s += t;
  t = __uint_as_float(__builtin_amdgcn_update_dpp(
      0, (int)__float_as_uint(s), 0x4E /*[2,3,0,1]*/, 0xF, 0xF, true));
  s += t;
  return s;
}

// ---------------------------------------------------------------------------
// K-1: runtime dtype detector (fp32 confirmed on this dataset; kept for
// robustness, ~3 us).
// ---------------------------------------------------------------------------
__global__ void k_detect(const u32* __restrict__ raw, int* __restrict__ flagp) {
  const int t = threadIdx.x;
  int zlo = 0, hits = 0;
  for (int k = t; k < 256; k += 64) {
    u32 w = raw[k];
    if ((w & 0xFFFFu) == 0u) zlo++;
    u32 m = (w >> 8) & 0x7Fu;
    if (m >= 40u && m <= 70u) hits++;
  }
#pragma unroll
  for (int off = 32; off; off >>= 1) {
    zlo += __shfl_down(zlo, off, 64);
    hits += __shfl_down(hits, off, 64);
  }
  if (t == 0) *flagp = (zlo < 128 && hits >= 128) ? 1 : 0;
}

// ---------------------------------------------------------------------------
// K0: convert weights/biases (+ t=255 slices) to fp32; Wm/Wu/Wg/Wa transposed.
// ---------------------------------------------------------------------------
__global__ __launch_bounds__(256) void k_convert(
    const void* nodes, const void* gattr,
    const void* Wm, const void* Whm, const void* bm1, const void* bm2,
    const void* Wu, const void* Whu, const void* bu1, const void* bu2,
    const void* Wg, const void* Whg, const void* bg1, const void* bg2,
    const void* Wa, const void* Wha, const void* ba1, const void* ba2,
    const int* __restrict__ flagp, float* __restrict__ dst) {
  const int flag = *flagp;
  const int i = blockIdx.x * 256 + threadIdx.x;
  if (i >= CONV_TOTAL) return;
  float v;
  if (i < O_GA) {
    int n = i >> 6, f = i & 63;
    v = cvt(nodes, (n * TT + (TT - 1)) * FN + f, flag);
  } else if (i < O_WM) {
    int l = i - O_GA; int b = l >> 4, g = l & 15;
    v = cvt(gattr, (b * TT + (TT - 1)) * FG + g, flag);
  } else if (i < O_WHM) {
    int l = i - O_WM; int d = l >> 9, j = l & 511;   // WmT[d][j]
    v = cvt(Wm, j * DM + d, flag);
  } else if (i < O_BM) {
    v = cvt(Whm, i - O_WHM, flag);
  } else if (i < O_WU) {
    int l = i - O_BM; v = cvt(bm1, l, flag) + cvt(bm2, l, flag);
  } else if (i < O_WHU) {
    int l = i - O_WU; int d = l >> 9, j = l & 511;   // WuT[d][j]
    v = cvt(Wu, j * DU + d, flag);
  } else if (i < O_BU) {
    v = cvt(Whu, i - O_WHU, flag);
  } else if (i < O_WG) {
    int l = i - O_BU; v = cvt(bu1, l, flag) + cvt(bu2, l, flag);
  } else if (i < O_WHG) {
    int l = i - O_WG; int d = l >> 8, j = l & 255;   // WgT[d][j]
    v = cvt(Wg, j * DG + d, flag);
  } else if (i < O_BG2) {
    v = cvt(Whg, i - O_WHG, flag);
  } else if (i < O_WA) {
    int l = i - O_BG2; v = cvt(bg1, l, flag) + cvt(bg2, l, flag);
  } else if (i < O_WHA) {
    int l = i - O_WA; int d = l >> 4, j = l & 15;    // WaT[d][j]
    v = cvt(Wa, j * DA + d, flag);
  } else if (i < O_BA) {
    v = cvt(Wha, i - O_WHA, flag);
  } else {
    int l = i - O_BA; v = cvt(ba1, l, flag) + cvt(ba2, l, flag);
  }
  dst[i] = v;
}

// ---------------------------------------------------------------------------
// K1: input projections at t=T-1 with transposed weights (coalesced).
// blocks [0,320): XZmU per unique node; [320,640): XZu; [640,704): XZg
// ---------------------------------------------------------------------------
__global__ __launch_bounds__(256) void k_pre(
    const float* __restrict__ cva, const int* __restrict__ num_nodes,
    float* __restrict__ XZmU, float* __restrict__ XZu, float* __restrict__ XZg) {
  const int blk = blockIdx.x, tid = threadIdx.x;
  __shared__ float xv[FN];
  __shared__ float gav[FG];
  __shared__ int sgr;
  const float* nodes255 = cva + O_NODES;
  const float* ga255 = cva + O_GA;

  if (blk < 2 * NNODE) {
    const int n = (blk < NNODE) ? blk : (blk - NNODE);
    if (tid == 0) {
      int g = 0, acc = 0;
      while (g < BG) { int c = num_nodes[g]; if (n < acc + c) break; acc += c; ++g; }
      if (g >= BG) g = BG - 1;
      sgr = g;
    }
    if (tid < FN) xv[tid] = nodes255[n * FN + tid];
    __syncthreads();
    if (tid < FG) gav[tid] = ga255[sgr * FG + tid];
    __syncthreads();
    const int j0 = 2 * tid;
    if (blk < NNODE) {
      float2 acc = *(const float2*)&cva[O_BM + j0];
#pragma unroll 8
      for (int d = 0; d < FN; ++d) {
        float2 wa = *(const float2*)&cva[O_WM + d * 512 + j0];
        float2 wb = *(const float2*)&cva[O_WM + (FN + d) * 512 + j0];
        float x = xv[d];
        acc.x += (wa.x + wb.x) * x;
        acc.y += (wa.y + wb.y) * x;
      }
#pragma unroll
      for (int d = 0; d < FG; ++d) {
        float2 wc = *(const float2*)&cva[O_WM + (2 * FN + d) * 512 + j0];
        float x = gav[d];
        acc.x += wc.x * x;
        acc.y += wc.y * x;
      }
      *(float2*)&XZmU[(size_t)n * ZM + j0] = acc;
    } else {
      float2 acc = *(const float2*)&cva[O_BU + j0];
#pragma unroll 8
      for (int d = 0; d < FN; ++d) {
        float2 wa = *(const float2*)&cva[O_WU + d * 512 + j0];
        float x = xv[d];
        acc.x += wa.x * x;
        acc.y += wa.y * x;
      }
#pragma unroll
      for (int d = 0; d < FG; ++d) {
        float2 wc = *(const float2*)&cva[O_WU + (FN + HM + d) * 512 + j0];
        float x = gav[d];
        acc.x += wc.x * x;
        acc.y += wc.y * x;
      }
      *(float2*)&XZu[(size_t)n * ZU + j0] = acc;
    }
  } else {
    const int b = blk - 2 * NNODE;
    if (tid < FG) gav[tid] = ga255[b * FG + tid];
    __syncthreads();
    float acc = cva[O_BG2 + tid];
#pragma unroll
    for (int d = 0; d < FG; ++d)
      acc += cva[O_WG + (HU + d) * 256 + tid] * gav[d];
    XZg[(size_t)b * ZG + tid] = acc;
  }
}

// ---------------------------------------------------------------------------
// K2/K4: LSTM chain, lane-parallel-k. 512 threads, 1 block, weights in VGPRs.
// Group = quad (kc = lane&3 -> 32-col chunk). Thread computes 4 rows
// {p*128+elem} x cols [kc*32,kc*32+32). Quad butterfly via DPP (VALU pipe).
// h double-buffered in padded LDS (4 chunks x 36 -> conflict-free b128).
// ONE lgkmcnt-only barrier per step. IDX: XZ row = eidx[e] (deduped XZm).
// ---------------------------------------------------------------------------
template <int STEPS, bool IDX>
__global__ __launch_bounds__(512, 1) void k_chain(
    const float* __restrict__ Whh, const float* __restrict__ XZ,
    const int* __restrict__ eidx, float* __restrict__ hout) {
  const int lane = threadIdx.x & 63;
  const int wv = threadIdx.x >> 6;
  const int kc = lane & 3;
  const int g = lane >> 2;
  const int elem = wv * 16 + g;
  __shared__ float hbuf[2][144];

  float4 wq[32];  // 128 floats: rows {p*128+elem}, cols kc*32..+31
#pragma unroll
  for (int p = 0; p < 4; ++p) {
    const float4* wr = (const float4*)(Whh + (size_t)(p * 128 + elem) * 128 + kc * 32);
#pragma unroll
    for (int q = 0; q < 8; ++q) wq[p * 8 + q] = wr[q];
  }
  if (threadIdx.x < 144) hbuf[0][threadIdx.x] = 0.0f;
  float c = 0.0f;
  float xz[4];
  {
    const int s0 = IDX ? eidx[0] : 0;
#pragma unroll
    for (int p = 0; p < 4; ++p) xz[p] = XZ[(size_t)s0 * 512 + p * 128 + elem];
  }
  BAR();
  int cur = 0;
  for (int e = 0; e < STEPS; ++e) {
    float4 hq[8];
    const float4* hb = (const float4*)&hbuf[cur][kc * 36];
#pragma unroll
    for (int q = 0; q < 8; ++q) hq[q] = hb[q];
    float z[4];
#pragma unroll
    for (int p = 0; p < 4; ++p) {
      float ax = 0.0f, ay = 0.0f, az = 0.0f, aw = 0.0f;
#pragma unroll
      for (int q = 0; q < 8; ++q) {
        ax += wq[p * 8 + q].x * hq[q].x;
        ay += wq[p * 8 + q].y * hq[q].y;
        az += wq[p * 8 + q].z * hq[q].z;
        aw += wq[p * 8 + q].w * hq[q].w;
      }
      z[p] = xz[p] + quad_sum((ax + ay) + (az + aw));
    }
    if (e + 1 < STEPS) {
      const int sn = IDX ? eidx[e + 1] : (e + 1);
      const float* xp = XZ + (size_t)sn * 512;
#pragma unroll
      for (int p = 0; p < 4; ++p) xz[p] = xp[p * 128 + elem];
    }
    // gates: z[0]=i, z[1]=f, z[2]=g, z[3]=o (replicated across the quad)
    c = sigf(z[1]) * c + sigf(z[0]) * tanh_(z[2]);
    float h = sigf(z[3]) * tanh_(c);
    if (kc == 0) {
      hbuf[cur ^ 1][(elem >> 5) * 36 + (elem & 31)] = h;
      hout[(size_t)e * 128 + elem] = fmaxf(h, 0.0f);
    }
    BAR();
    cur ^= 1;
  }
}

// ---------------------------------------------------------------------------
// K3: fused segment_min + projection: aggr[n]=min msg over eidx==n (LDS),
// then XZu[n] += WuT[64:192] @ aggr[n]. 320 blocks x 256 threads.
// ---------------------------------------------------------------------------
__global__ __launch_bounds__(256) void k_aggfuse(
    const float* __restrict__ cva, const float* __restrict__ msg,
    const int* __restrict__ eidx, float* __restrict__ XZu) {
  const int n = blockIdx.x, tid = threadIdx.x;
  __shared__ float av[HM];
  if (tid < HM) {
    float m = __uint_as_float(0x7f800000u);
    for (int e = 0; e < NEDGE; ++e)
      if (eidx[e] == n) m = fminf(m, msg[(size_t)e * HM + tid]);
    av[tid] = m;
  }
  __syncthreads();
  const int j0 = 2 * tid;
  float2 acc = *(float2*)&XZu[(size_t)n * ZU + j0];
#pragma unroll 8
  for (int k = 0; k < HM; ++k) {
    float2 w = *(const float2*)&cva[O_WU + (FN + k) * 512 + j0];
    float a = av[k];
    acc.x += w.x * a;
    acc.y += w.y * a;
  }
  *(float2*)&XZu[(size_t)n * ZU + j0] = acc;
}

// ---------------------------------------------------------------------------
// K5: blocks [0,64): XZg[b] += WgT[0:128] @ aggB[b] (aggB computed locally)
//     blocks [64,128): XZa[b] = WaT[0:128] @ chosen[b] + biases
// ---------------------------------------------------------------------------
__global__ __launch_bounds__(256) void k_gproj(
    const float* __restrict__ cva, const float* __restrict__ upd,
    const int* __restrict__ bidx, const int* __restrict__ who,
    float* __restrict__ XZg, float* __restrict__ XZa) {
  const int blk = blockIdx.x, tid = threadIdx.x;
  const int b = (blk < BG) ? blk : (blk - BG);
  __shared__ float buf[HU];   // local aggB[b]
  __shared__ float cho[HU];
  __shared__ int satbw;
  if (tid < HU) {
    float m = __uint_as_float(0x7f800000u);
    for (int nn = 0; nn < NNODE; ++nn)
      if (bidx[nn] == b) m = fminf(m, upd[(size_t)nn * HU + tid]);
    buf[tid] = m;
  }
  __syncthreads();
  if (blk < BG) {
    float acc = 0.0f;
#pragma unroll 8
    for (int k = 0; k < HU; ++k) acc += cva[O_WG + k * 256 + tid] * buf[k];
    XZg[(size_t)b * ZG + tid] += acc;
  } else {
    const int whoB = who[b];
    if (tid == 0) {
      int off = 0;
      for (int i = 0; i < NNODE; ++i) off += (bidx[i] < b) ? 1 : 0;
      const int adj = (whoB == 3) ? 2 : whoB;
      satbw = (b == 0) ? who[0] : (adj + off);
    }
    __syncthreads();
    if (tid < HU) cho[tid] = (whoB == 3) ? buf[tid] : upd[(size_t)satbw * HU + tid];
    __syncthreads();
    if (tid < ZA) {
      float acc = cva[O_BA + tid];
#pragma unroll 8
      for (int k = 0; k < HU; ++k) acc += cva[O_WA + k * 16 + tid] * cho[k];
      XZa[(size_t)b * ZA + tid] = acc;
    }
  }
}

// ---------------------------------------------------------------------------
// K6: group LSTM chain + action chain + softmax + fp32 out. 1 block x 256.
// ---------------------------------------------------------------------------
__global__ __launch_bounds__(256, 2) void k_final(
    const float* __restrict__ cva, const float* __restrict__ XZg,
    const float* __restrict__ XZa, float* __restrict__ out) {
  const int j = threadIdx.x;
  __shared__ __align__(16) float hg[HG];
  __shared__ float zsg[ZG];
  __shared__ float grp[BG * HG];
  __shared__ float za[ZA];
  __shared__ float haL[HA];
  __shared__ float res[BG * HA];

  float wg[HG];
  {
    const float* wr = cva + O_WHG + j * HG;
#pragma unroll
    for (int k = 0; k < HG; ++k) wg[k] = wr[k];
  }
  if (j < HG) hg[j] = 0.0f;
  float cg = 0.0f;
  __syncthreads();
  for (int b = 0; b < BG; ++b) {
    float acc = XZg[(size_t)b * ZG + j];
#pragma unroll
    for (int k = 0; k < HG; ++k) acc += wg[k] * hg[k];
    zsg[j] = acc;
    __syncthreads();
    if (j < HG) {
      float zi = zsg[j], zf = zsg[HG + j], zg = zsg[2 * HG + j], zo = zsg[3 * HG + j];
      cg = sigf(zf) * cg + sigf(zi) * tanh_(zg);
      float h = sigf(zo) * tanh_(cg);
      hg[j] = h;
      grp[b * HG + j] = fmaxf(h, 0.0f);
    }
    __syncthreads();
  }

  float wa2[HG];
  float wha[HA];
  if (j < ZA) {
#pragma unroll
    for (int k = 0; k < HG; ++k) wa2[k] = cva[O_WA + (HU + k) * 16 + j];
#pragma unroll
    for (int k = 0; k < HA; ++k) wha[k] = cva[O_WHA + j * HA + k];
  }
  if (j < HA) haL[j] = 0.0f;
  float ca = 0.0f;
  __syncthreads();
  for (int b = 0; b < BG; ++b) {
    if (j < ZA) {
      float acc = XZa[(size_t)b * ZA + j];
#pragma unroll
      for (int k = 0; k < HG; ++k) acc += wa2[k] * grp[b * HG + k];
#pragma unroll
      for (int k = 0; k < HA; ++k) acc += wha[k] * haL[k];
      za[j] = acc;
    }
    __syncthreads();
    if (j < HA) {
      float zi = za[j], zf = za[HA + j], zg = za[2 * HA + j], zo = za[3 * HA + j];
      ca = sigf(zf) * ca + sigf(zi) * tanh_(zg);
      float h = sigf(zo) * tanh_(ca);
      haL[j] = h;
      res[b * HA + j] = h;
    }
    __syncthreads();
  }
  if (j < BG) {
    float x0 = res[j * 4 + 0], x1 = res[j * 4 + 1];
    float x2 = res[j * 4 + 2], x3 = res[j * 4 + 3];
    float m = fmaxf(fmaxf(x0, x1), fmaxf(x2, x3));
    float e0 = __expf(x0 - m), e1 = __expf(x1 - m);
    float e2 = __expf(x2 - m), e3 = __expf(x3 - m);
    float s = e0 + e1 + e2 + e3;
    out[j * 4 + 0] = e0 / s;
    out[j * 4 + 1] = e1 / s;
    out[j * 4 + 2] = e2 / s;
    out[j * 4 + 3] = e3 / s;
  }
}

__global__ void k_zero(float* out) { out[threadIdx.x] = 0.0f; }

extern "C" void kernel_launch(void* const* d_in, const int* in_sizes, int n_in,
                              void* d_out, int out_size, void* d_ws, size_t ws_size,
                              hipStream_t stream) {
  const void* nodes = d_in[0];
  const int* eidx  = (const int*)d_in[2];
  const int* nn    = (const int*)d_in[3];
  const int* bidx  = (const int*)d_in[5];
  const int* who   = (const int*)d_in[6];

  if (ws_size < (size_t)WS_FLOATS * 4) {
    k_zero<<<1, 256, 0, stream>>>((float*)d_out);
    return;
  }

  float* ws = (float*)d_ws;
  int* flagp = (int*)d_ws;
  float* cva = ws + CV;
  float* XZmU = cva + O_XZM;   // 320 x 512 (unique per src node)
  float* msg  = cva + O_MSG;   // 1280 x 128
  float* XZu = cva + O_XZU;
  float* XZg = cva + O_XZG;
  float* XZa = cva + O_XZA;
  float* upd = cva + O_UPD;

  k_detect<<<1, 64, 0, stream>>>((const u32*)nodes, flagp);
  k_convert<<<(CONV_TOTAL + 255) / 256, 256, 0, stream>>>(
      nodes, d_in[1],
      d_in[7], d_in[8], d_in[9], d_in[10],
      d_in[11], d_in[12], d_in[13], d_in[14],
      d_in[15], d_in[16], d_in[17], d_in[18],
      d_in[19], d_in[20], d_in[21], d_in[22],
      flagp, cva);
  k_pre<<<2 * NNODE + BG, 256, 0, stream>>>(cva, nn, XZmU, XZu, XZg);
  k_chain<NEDGE, true><<<1, 512, 0, stream>>>(cva + O_WHM, XZmU, eidx, msg);
  k_aggfuse<<<NNODE, 256, 0, stream>>>(cva, msg, eidx, XZu);
  k_chain<NNODE, false><<<1, 512, 0, stream>>>(cva + O_WHU, XZu, nullptr, upd);
  k_gproj<<<2 * BG, 256, 0, stream>>>(cva, upd, bidx, who, XZg, XZa);
  k_final<<<1, 256, 0, stream>>>(cva, XZg, XZa, (float*)d_out);
}

// Round 8
// 2315.140 us; speedup vs baseline: 1.0071x; 1.0071x over previous
//
#include <hip/hip_runtime.h>

typedef unsigned int u32;
typedef unsigned short u16;

#define BG 64
#define NNODE 320
#define NEDGE 1280
#define TT 256
#define FN 64
#define FG 16
#define HM 128
#define HU 128
#define HG 64
#define HA 4
#define ZM 512
#define ZU 512
#define ZG 256
#define ZA 16
#define DM 144
#define DU 208
#define DG 144
#define DA 192

// ---- conversion-area layout (floats, relative to ws+64) ----
// WmT/WuT/WgT/WaT are stored TRANSPOSED (din-major) for coalesced projection
// kernels. Whh_m/Whh_u/Whg/Wha stay row-major (per-thread register loads).
#define CV 64
#define O_NODES 0
#define O_GA    20480
#define O_WM    21504
#define O_WHM   95232
#define O_BM    160768
#define O_WU    161280
#define O_WHU   267776
#define O_BU    333312
#define O_WG    333824
#define O_WHG   370688
#define O_BG2   387072
#define O_WA    387328
#define O_WHA   390400
#define O_BA    390464
#define CONV_TOTAL 390480
#define O_XZM   390528
#define O_MSG   (O_XZM + 320 * ZM)
#define O_XZU   (O_XZM + NEDGE * ZM)
#define O_XZG   (O_XZU + NNODE * ZU)
#define O_XZA   (O_XZG + BG * ZG)
#define O_AGGR  (O_XZA + BG * ZA)
#define O_AGGB  (O_AGGR + NNODE * HM)
#define O_UPD   (O_AGGB + BG * HU)
#define WS_FLOATS (CV + O_UPD + NNODE * HU)

__device__ __forceinline__ float bf2f(u16 v) {
  return __uint_as_float(((u32)v) << 16);
}
__device__ __forceinline__ float sigf(float x) { return 1.0f / (1.0f + __expf(-x)); }
__device__ __forceinline__ float tanh_(float x) {
  float e = __expf(-2.0f * fabsf(x));
  float t = (1.0f - e) / (1.0f + e);
  return copysignf(t, x);
}
__device__ __forceinline__ float cvt(const void* p, int i, int flag) {
  return flag ? bf2f(((const u16*)p)[i]) : ((const float*)p)[i];
}

// lgkmcnt-only barrier: orders LDS without __syncthreads()'s vmcnt(0) drain.
#define BAR() asm volatile("s_waitcnt lgkmcnt(0)\n\ts_barrier" ::: "memory")

// 4-lane (quad) butterfly sum on the VALU pipe via DPP quad_perm — no DS ops.
__device__ __forceinline__ float quad_sum(float s) {
  float t;
  t = __uint_as_float(__builtin_amdgcn_update_dpp(
      0, (int)__float_as_uint(s), 0xB1 /*[1,0,3,2]*/, 0xF, 0xF, true));
  s += t;
  t = __uint_as_float(__builtin_amdgcn_update_dpp(
      0, (int)__float_as_uint(s), 0x4E /*[2,3,0,1]*/, 0xF, 0xF, true));
  s += t;
  return s;
}

// ---------------------------------------------------------------------------
// K-1: runtime dtype detector (fp32 confirmed on this dataset; kept for
// robustness, ~3 us).
// ---------------------------------------------------------------------------
__global__ void k_detect(const u32* __restrict__ raw, int* __restrict__ flagp) {
  const int t = threadIdx.x;
  int zlo = 0, hits = 0;
  for (int k = t; k < 256; k += 64) {
    u32 w = raw[k];
    if ((w & 0xFFFFu) == 0u) zlo++;
    u32 m = (w >> 8) & 0x7Fu;
    if (m >= 40u && m <= 70u) hits++;
  }
#pragma unroll
  for (int off = 32; off; off >>= 1) {
    zlo += __shfl_down(zlo, off, 64);
    hits += __shfl_down(hits, off, 64);
  }
  if (t == 0) *flagp = (zlo < 128 && hits >= 128) ? 1 : 0;
}

// ---------------------------------------------------------------------------
// K0: convert weights/biases (+ t=255 slices) to fp32; Wm/Wu/Wg/Wa transposed.
// ---------------------------------------------------------------------------
__global__ __launch_bounds__(256) void k_convert(
    const void* nodes, const void* gattr,
    const void* Wm, const void* Whm, const void* bm1, const void* bm2,
    const void* Wu, const void* Whu, const void* bu1, const void* bu2,
    const void* Wg, const void* Whg, const void* bg1, const void* bg2,
    const void* Wa, const void* Wha, const void* ba1, const void* ba2,
    const int* __restrict__ flagp, float* __restrict__ dst) {
  const int flag = *flagp;
  const int i = blockIdx.x * 256 + threadIdx.x;
  if (i >= CONV_TOTAL) return;
  float v;
  if (i < O_GA) {
    int n = i >> 6, f = i & 63;
    v = cvt(nodes, (n * TT + (TT - 1)) * FN + f, flag);
  } else if (i < O_WM) {
    int l = i - O_GA; int b = l >> 4, g = l & 15;
    v = cvt(gattr, (b * TT + (TT - 1)) * FG + g, flag);
  } else if (i < O_WHM) {
    int l = i - O_WM; int d = l >> 9, j = l & 511;   // WmT[d][j]
    v = cvt(Wm, j * DM + d, flag);
  } else if (i < O_BM) {
    v = cvt(Whm, i - O_WHM, flag);
  } else if (i < O_WU) {
    int l = i - O_BM; v = cvt(bm1, l, flag) + cvt(bm2, l, flag);
  } else if (i < O_WHU) {
    int l = i - O_WU; int d = l >> 9, j = l & 511;   // WuT[d][j]
    v = cvt(Wu, j * DU + d, flag);
  } else if (i < O_BU) {
    v = cvt(Whu, i - O_WHU, flag);
  } else if (i < O_WG) {
    int l = i - O_BU; v = cvt(bu1, l, flag) + cvt(bu2, l, flag);
  } else if (i < O_WHG) {
    int l = i - O_WG; int d = l >> 8, j = l & 255;   // WgT[d][j]
    v = cvt(Wg, j * DG + d, flag);
  } else if (i < O_BG2) {
    v = cvt(Whg, i - O_WHG, flag);
  } else if (i < O_WA) {
    int l = i - O_BG2; v = cvt(bg1, l, flag) + cvt(bg2, l, flag);
  } else if (i < O_WHA) {
    int l = i - O_WA; int d = l >> 4, j = l & 15;    // WaT[d][j]
    v = cvt(Wa, j * DA + d, flag);
  } else if (i < O_BA) {
    v = cvt(Wha, i - O_WHA, flag);
  } else {
    int l = i - O_BA; v = cvt(ba1, l, flag) + cvt(ba2, l, flag);
  }
  dst[i] = v;
}

// ---------------------------------------------------------------------------
// K1: input projections at t=T-1 with transposed weights (coalesced).
// blocks [0,320): XZmU per unique node; [320,640): XZu; [640,704): XZg
// ---------------------------------------------------------------------------
__global__ __launch_bounds__(256) void k_pre(
    const float* __restrict__ cva, const int* __restrict__ num_nodes,
    float* __restrict__ XZmU, float* __restrict__ XZu, float* __restrict__ XZg) {
  const int blk = blockIdx.x, tid = threadIdx.x;
  __shared__ float xv[FN];
  __shared__ float gav[FG];
  __shared__ int sgr;
  const float* nodes255 = cva + O_NODES;
  const float* ga255 = cva + O_GA;

  if (blk < 2 * NNODE) {
    const int n = (blk < NNODE) ? blk : (blk - NNODE);
    if (tid == 0) {
      int g = 0, acc = 0;
      while (g < BG) { int c = num_nodes[g]; if (n < acc + c) break; acc += c; ++g; }
      if (g >= BG) g = BG - 1;
      sgr = g;
    }
    if (tid < FN) xv[tid] = nodes255[n * FN + tid];
    __syncthreads();
    if (tid < FG) gav[tid] = ga255[sgr * FG + tid];
    __syncthreads();
    const int j0 = 2 * tid;
    if (blk < NNODE) {
      float2 acc = *(const float2*)&cva[O_BM + j0];
#pragma unroll 8
      for (int d = 0; d < FN; ++d) {
        float2 wa = *(const float2*)&cva[O_WM + d * 512 + j0];
        float2 wb = *(const float2*)&cva[O_WM + (FN + d) * 512 + j0];
        float x = xv[d];
        acc.x += (wa.x + wb.x) * x;
        acc.y += (wa.y + wb.y) * x;
      }
#pragma unroll
      for (int d = 0; d < FG; ++d) {
        float2 wc = *(const float2*)&cva[O_WM + (2 * FN + d) * 512 + j0];
        float x = gav[d];
        acc.x += wc.x * x;
        acc.y += wc.y * x;
      }
      *(float2*)&XZmU[(size_t)n * ZM + j0] = acc;
    } else {
      float2 acc = *(const float2*)&cva[O_BU + j0];
#pragma unroll 8
      for (int d = 0; d < FN; ++d) {
        float2 wa = *(const float2*)&cva[O_WU + d * 512 + j0];
        float x = xv[d];
        acc.x += wa.x * x;
        acc.y += wa.y * x;
      }
#pragma unroll
      for (int d = 0; d < FG; ++d) {
        float2 wc = *(const float2*)&cva[O_WU + (FN + HM + d) * 512 + j0];
        float x = gav[d];
        acc.x += wc.x * x;
        acc.y += wc.y * x;
      }
      *(float2*)&XZu[(size_t)n * ZU + j0] = acc;
    }
  } else {
    const int b = blk - 2 * NNODE;
    if (tid < FG) gav[tid] = ga255[b * FG + tid];
    __syncthreads();
    float acc = cva[O_BG2 + tid];
#pragma unroll
    for (int d = 0; d < FG; ++d)
      acc += cva[O_WG + (HU + d) * 256 + tid] * gav[d];
    XZg[(size_t)b * ZG + tid] = acc;
  }
}

// ---------------------------------------------------------------------------
// K2/K4: LSTM chain, lane-parallel-k. 512 threads, 1 block, weights in VGPRs.
// amdgpu_waves_per_eu(1,2): relax the backend's occupancy heuristic so the
// allocator may use up to 256 VGPRs/wave (block = 8 waves = exactly 2/EU,
// grid = 1 block, so occupancy is unaffected). Without this the allocator
// targets default high occupancy and SPILLS the 128-float weight array
// (rounds 5-7: VGPR=84/96, FETCH=0.5-1.4 GB of scratch traffic).
// ---------------------------------------------------------------------------
template <int STEPS, bool IDX>
__global__ __attribute__((amdgpu_waves_per_eu(1, 2))) __launch_bounds__(512)
void k_chain(
    const float* __restrict__ Whh, const float* __restrict__ XZ,
    const int* __restrict__ eidx, float* __restrict__ hout) {
  const int lane = threadIdx.x & 63;
  const int wv = threadIdx.x >> 6;
  const int kc = lane & 3;
  const int g = lane >> 2;
  const int elem = wv * 16 + g;
  __shared__ float hbuf[2][144];

  float4 wq[32];  // 128 floats: rows {p*128+elem}, cols kc*32..+31
#pragma unroll
  for (int p = 0; p < 4; ++p) {
    const float4* wr = (const float4*)(Whh + (size_t)(p * 128 + elem) * 128 + kc * 32);
#pragma unroll
    for (int q = 0; q < 8; ++q) wq[p * 8 + q] = wr[q];
  }
  if (threadIdx.x < 144) hbuf[0][threadIdx.x] = 0.0f;
  float c = 0.0f;
  float xz[4];
  {
    const int s0 = IDX ? eidx[0] : 0;
#pragma unroll
    for (int p = 0; p < 4; ++p) xz[p] = XZ[(size_t)s0 * 512 + p * 128 + elem];
  }
  BAR();
  int cur = 0;
  for (int e = 0; e < STEPS; ++e) {
    float4 hq[8];
    const float4* hb = (const float4*)&hbuf[cur][kc * 36];
#pragma unroll
    for (int q = 0; q < 8; ++q) hq[q] = hb[q];
    float z[4];
#pragma unroll
    for (int p = 0; p < 4; ++p) {
      float ax = 0.0f, ay = 0.0f, az = 0.0f, aw = 0.0f;
#pragma unroll
      for (int q = 0; q < 8; ++q) {
        ax += wq[p * 8 + q].x * hq[q].x;
        ay += wq[p * 8 + q].y * hq[q].y;
        az += wq[p * 8 + q].z * hq[q].z;
        aw += wq[p * 8 + q].w * hq[q].w;
      }
      z[p] = xz[p] + quad_sum((ax + ay) + (az + aw));
    }
    if (e + 1 < STEPS) {
      const int sn = IDX ? eidx[e + 1] : (e + 1);
      const float* xp = XZ + (size_t)sn * 512;
#pragma unroll
      for (int p = 0; p < 4; ++p) xz[p] = xp[p * 128 + elem];
    }
    // gates: z[0]=i, z[1]=f, z[2]=g, z[3]=o (replicated across the quad)
    c = sigf(z[1]) * c + sigf(z[0]) * tanh_(z[2]);
    float h = sigf(z[3]) * tanh_(c);
    if (kc == 0) {
      hbuf[cur ^ 1][(elem >> 5) * 36 + (elem & 31)] = h;
      hout[(size_t)e * 128 + elem] = fmaxf(h, 0.0f);
    }
    BAR();
    cur ^= 1;
  }
}

// ---------------------------------------------------------------------------
// K3: fused segment_min + projection: aggr[n]=min msg over eidx==n (LDS),
// then XZu[n] += WuT[64:192] @ aggr[n]. 320 blocks x 256 threads.
// ---------------------------------------------------------------------------
__global__ __launch_bounds__(256) void k_aggfuse(
    const float* __restrict__ cva, const float* __restrict__ msg,
    const int* __restrict__ eidx, float* __restrict__ XZu) {
  const int n = blockIdx.x, tid = threadIdx.x;
  __shared__ float av[HM];
  if (tid < HM) {
    float m = __uint_as_float(0x7f800000u);
    for (int e = 0; e < NEDGE; ++e)
      if (eidx[e] == n) m = fminf(m, msg[(size_t)e * HM + tid]);
    av[tid] = m;
  }
  __syncthreads();
  const int j0 = 2 * tid;
  float2 acc = *(float2*)&XZu[(size_t)n * ZU + j0];
#pragma unroll 8
  for (int k = 0; k < HM; ++k) {
    float2 w = *(const float2*)&cva[O_WU + (FN + k) * 512 + j0];
    float a = av[k];
    acc.x += w.x * a;
    acc.y += w.y * a;
  }
  *(float2*)&XZu[(size_t)n * ZU + j0] = acc;
}

// ---------------------------------------------------------------------------
// K5: blocks [0,64): XZg[b] += WgT[0:128] @ aggB[b] (aggB computed locally)
//     blocks [64,128): XZa[b] = WaT[0:128] @ chosen[b] + biases
// ---------------------------------------------------------------------------
__global__ __launch_bounds__(256) void k_gproj(
    const float* __restrict__ cva, const float* __restrict__ upd,
    const int* __restrict__ bidx, const int* __restrict__ who,
    float* __restrict__ XZg, float* __restrict__ XZa) {
  const int blk = blockIdx.x, tid = threadIdx.x;
  const int b = (blk < BG) ? blk : (blk - BG);
  __shared__ float buf[HU];   // local aggB[b]
  __shared__ float cho[HU];
  __shared__ int satbw;
  if (tid < HU) {
    float m = __uint_as_float(0x7f800000u);
    for (int nn = 0; nn < NNODE; ++nn)
      if (bidx[nn] == b) m = fminf(m, upd[(size_t)nn * HU + tid]);
    buf[tid] = m;
  }
  __syncthreads();
  if (blk < BG) {
    float acc = 0.0f;
#pragma unroll 8
    for (int k = 0; k < HU; ++k) acc += cva[O_WG + k * 256 + tid] * buf[k];
    XZg[(size_t)b * ZG + tid] += acc;
  } else {
    const int whoB = who[b];
    if (tid == 0) {
      int off = 0;
      for (int i = 0; i < NNODE; ++i) off += (bidx[i] < b) ? 1 : 0;
      const int adj = (whoB == 3) ? 2 : whoB;
      satbw = (b == 0) ? who[0] : (adj + off);
    }
    __syncthreads();
    if (tid < HU) cho[tid] = (whoB == 3) ? buf[tid] : upd[(size_t)satbw * HU + tid];
    __syncthreads();
    if (tid < ZA) {
      float acc = cva[O_BA + tid];
#pragma unroll 8
      for (int k = 0; k < HU; ++k) acc += cva[O_WA + k * 16 + tid] * cho[k];
      XZa[(size_t)b * ZA + tid] = acc;
    }
  }
}

// ---------------------------------------------------------------------------
// K6: group LSTM chain + action chain + softmax + fp32 out. 1 block x 256.
// ---------------------------------------------------------------------------
__global__ __launch_bounds__(256, 2) void k_final(
    const float* __restrict__ cva, const float* __restrict__ XZg,
    const float* __restrict__ XZa, float* __restrict__ out) {
  const int j = threadIdx.x;
  __shared__ __align__(16) float hg[HG];
  __shared__ float zsg[ZG];
  __shared__ float grp[BG * HG];
  __shared__ float za[ZA];
  __shared__ float haL[HA];
  __shared__ float res[BG * HA];

  float wg[HG];
  {
    const float* wr = cva + O_WHG + j * HG;
#pragma unroll
    for (int k = 0; k < HG; ++k) wg[k] = wr[k];
  }
  if (j < HG) hg[j] = 0.0f;
  float cg = 0.0f;
  __syncthreads();
  for (int b = 0; b < BG; ++b) {
    float acc = XZg[(size_t)b * ZG + j];
#pragma unroll
    for (int k = 0; k < HG; ++k) acc += wg[k] * hg[k];
    zsg[j] = acc;
    __syncthreads();
    if (j < HG) {
      float zi = zsg[j], zf = zsg[HG + j], zg = zsg[2 * HG + j], zo = zsg[3 * HG + j];
      cg = sigf(zf) * cg + sigf(zi) * tanh_(zg);
      float h = sigf(zo) * tanh_(cg);
      hg[j] = h;
      grp[b * HG + j] = fmaxf(h, 0.0f);
    }
    __syncthreads();
  }

  float wa2[HG];
  float wha[HA];
  if (j < ZA) {
#pragma unroll
    for (int k = 0; k < HG; ++k) wa2[k] = cva[O_WA + (HU + k) * 16 + j];
#pragma unroll
    for (int k = 0; k < HA; ++k) wha[k] = cva[O_WHA + j * HA + k];
  }
  if (j < HA) haL[j] = 0.0f;
  float ca = 0.0f;
  __syncthreads();
  for (int b = 0; b < BG; ++b) {
    if (j < ZA) {
      float acc = XZa[(size_t)b * ZA + j];
#pragma unroll
      for (int k = 0; k < HG; ++k) acc += wa2[k] * grp[b * HG + k];
#pragma unroll
      for (int k = 0; k < HA; ++k) acc += wha[k] * haL[k];
      za[j] = acc;
    }
    __syncthreads();
    if (j < HA) {
      float zi = za[j], zf = za[HA + j], zg = za[2 * HA + j], zo = za[3 * HA + j];
      ca = sigf(zf) * ca + sigf(zi) * tanh_(zg);
      float h = sigf(zo) * tanh_(ca);
      haL[j] = h;
      res[b * HA + j] = h;
    }
    __syncthreads();
  }
  if (j < BG) {
    float x0 = res[j * 4 + 0], x1 = res[j * 4 + 1];
    float x2 = res[j * 4 + 2], x3 = res[j * 4 + 3];
    float m = fmaxf(fmaxf(x0, x1), fmaxf(x2, x3));
    float e0 = __expf(x0 - m), e1 = __expf(x1 - m);
    float e2 = __expf(x2 - m), e3 = __expf(x3 - m);
    float s = e0 + e1 + e2 + e3;
    out[j * 4 + 0] = e0 / s;
    out[j * 4 + 1] = e1 / s;
    out[j * 4 + 2] = e2 / s;
    out[j * 4 + 3] = e3 / s;
  }
}

__global__ void k_zero(float* out) { out[threadIdx.x] = 0.0f; }

extern "C" void kernel_launch(void* const* d_in, const int* in_sizes, int n_in,
                              void* d_out, int out_size, void* d_ws, size_t ws_size,
                              hipStream_t stream) {
  const void* nodes = d_in[0];
  const int* eidx  = (const int*)d_in[2];
  const int* nn    = (const int*)d_in[3];
  const int* bidx  = (const int*)d_in[5];
  const int* who   = (const int*)d_in[6];

  if (ws_size < (size_t)WS_FLOATS * 4) {
    k_zero<<<1, 256, 0, stream>>>((float*)d_out);
    return;
  }

  float* ws = (float*)d_ws;
  int* flagp = (int*)d_ws;
  float* cva = ws + CV;
  float* XZmU = cva + O_XZM;   // 320 x 512 (unique per src node)
  float* msg  = cva + O_MSG;   // 1280 x 128
  float* XZu = cva + O_XZU;
  float* XZg = cva + O_XZG;
  float* XZa = cva + O_XZA;
  float* upd = cva + O_UPD;

  k_detect<<<1, 64, 0, stream>>>((const u32*)nodes, flagp);
  k_convert<<<(CONV_TOTAL + 255) / 256, 256, 0, stream>>>(
      nodes, d_in[1],
      d_in[7], d_in[8], d_in[9], d_in[10],
      d_in[11], d_in[12], d_in[13], d_in[14],
      d_in[15], d_in[16], d_in[17], d_in[18],
      d_in[19], d_in[20], d_in[21], d_in[22],
      flagp, cva);
  k_pre<<<2 * NNODE + BG, 256, 0, stream>>>(cva, nn, XZmU, XZu, XZg);
  k_chain<NEDGE, true><<<1, 512, 0, stream>>>(cva + O_WHM, XZmU, eidx, msg);
  k_aggfuse<<<NNODE, 256, 0, stream>>>(cva, msg, eidx, XZu);
  k_chain<NNODE, false><<<1, 512, 0, stream>>>(cva + O_WHU, XZu, nullptr, upd);
  k_gproj<<<2 * BG, 256, 0, stream>>>(cva, upd, bidx, who, XZg, XZa);
  k_final<<<1, 256, 0, stream>>>(cva, XZg, XZa, (float*)d_out);
}